// Round 1
// baseline (636.922 us; speedup 1.0000x reference)
//
#include <hip/hip_runtime.h>
#include <math.h>

#define NN 10000
#define EE 160000
#define HID 128
constexpr int N128 = NN * HID;

// ---------------- degree / dinv ----------------
__global__ __launch_bounds__(256) void deg_count(const int* __restrict__ dst, float* __restrict__ deg) {
    int e = blockIdx.x * 256 + threadIdx.x;
    if (e < EE) atomicAdd(&deg[dst[e]], 1.0f);
}

__global__ __launch_bounds__(256) void make_dinv(float* deg) {
    int i = blockIdx.x * 256 + threadIdx.x;
    if (i < NN) deg[i] = rsqrtf(deg[i] + 1.0f);  // +1 for self-loop
}

// ---------------- fp32 GEMM: out[n][o] = sum_i act(in[n][i]) * W[i][o] + b[o] ----------------
struct GemmJob { const float* in; const float* W; const float* bias; float* out; };
struct GemmJobs { GemmJob j[7]; };

template<bool RELU_IN>
__global__ __launch_bounds__(256) void gemm128(GemmJobs jobs, int nrows) {
    const GemmJob jb = jobs.j[blockIdx.y];
    __shared__ float Xl[64][HID];
    __shared__ float Wl[32][HID];
    __shared__ float bl[HID];
    const int t = threadIdx.x;
    const int row0 = blockIdx.x * 64;

    // stage X tile (64 rows x 128) as float4, optional relu-on-load
    for (int i = t; i < 2048; i += 256) {
        int r = i >> 5, c4 = i & 31;
        float4 xv = make_float4(0.f, 0.f, 0.f, 0.f);
        int rr = row0 + r;
        if (rr < nrows) xv = ((const float4*)(jb.in + (size_t)rr * HID))[c4];
        if (RELU_IN) {
            xv.x = fmaxf(xv.x, 0.f); xv.y = fmaxf(xv.y, 0.f);
            xv.z = fmaxf(xv.z, 0.f); xv.w = fmaxf(xv.w, 0.f);
        }
        *((float4*)&Xl[r][c4 * 4]) = xv;
    }
    if (t < HID) bl[t] = jb.bias[t];

    const int tr = t >> 4, tc = t & 15;  // 16 row-groups x 16 col-groups
    float acc[4][8];
#pragma unroll
    for (int j = 0; j < 4; ++j)
#pragma unroll
        for (int c = 0; c < 8; ++c) acc[j][c] = 0.f;

    for (int ks = 0; ks < 4; ++ks) {  // W staged in 32-row quarters (fits 64KB LDS)
        __syncthreads();
        for (int i = t; i < 1024; i += 256) {
            int r = i >> 5, c4 = i & 31;
            *((float4*)&Wl[r][c4 * 4]) = ((const float4*)(jb.W + (size_t)(ks * 32 + r) * HID))[c4];
        }
        __syncthreads();
#pragma unroll
        for (int kk = 0; kk < 32; ++kk) {
            float xv[4];
#pragma unroll
            for (int j = 0; j < 4; ++j) xv[j] = Xl[tr * 4 + j][ks * 32 + kk];
            float4 w0 = *((const float4*)&Wl[kk][tc * 8]);
            float4 w1 = *((const float4*)&Wl[kk][tc * 8 + 4]);
            float w[8] = {w0.x, w0.y, w0.z, w0.w, w1.x, w1.y, w1.z, w1.w};
#pragma unroll
            for (int j = 0; j < 4; ++j)
#pragma unroll
                for (int c = 0; c < 8; ++c)
                    acc[j][c] = fmaf(xv[j], w[c], acc[j][c]);
        }
    }

#pragma unroll
    for (int j = 0; j < 4; ++j) {
        int rr = row0 + tr * 4 + j;
        if (rr < nrows) {
            float4 o0, o1;
            o0.x = acc[j][0] + bl[tc * 8 + 0];
            o0.y = acc[j][1] + bl[tc * 8 + 1];
            o0.z = acc[j][2] + bl[tc * 8 + 2];
            o0.w = acc[j][3] + bl[tc * 8 + 3];
            o1.x = acc[j][4] + bl[tc * 8 + 4];
            o1.y = acc[j][5] + bl[tc * 8 + 5];
            o1.z = acc[j][6] + bl[tc * 8 + 6];
            o1.w = acc[j][7] + bl[tc * 8 + 7];
            float4* op = (float4*)(jb.out + (size_t)rr * HID);
            op[tc * 2] = o0;
            op[tc * 2 + 1] = o1;
        }
    }
}

// ---------------- edge attention: one wave per edge ----------------
// lane i owns channels {2i, 2i+1}; head = i>>3; score reduce = shfl_xor 1,2,4 within 8 lanes
template<int L>
__global__ __launch_bounds__(256) void edge_attn(
    const int* __restrict__ ei, const float* __restrict__ dinv,
    const float* __restrict__ qn, const float* __restrict__ kn,
    const float* __restrict__ vn, float* __restrict__ aggout, int total) {
    int wid = (blockIdx.x * 256 + threadIdx.x) >> 6;
    int lane = threadIdx.x & 63;
    if (wid >= total) return;
    int s, d;
    if (wid < EE) { s = ei[wid]; d = ei[EE + wid]; }
    else { s = wid - EE; d = s; }
    float nm = dinv[s] * dinv[d];

    float2 q2 = ((const float2*)(qn + (size_t)d * HID))[lane];
    float sc[L];
    float2 v2[L];
#pragma unroll
    for (int l = 0; l < L; ++l) {
        float2 k2 = ((const float2*)(kn + (size_t)l * N128 + (size_t)s * HID))[lane];
        v2[l] = ((const float2*)(vn + (size_t)l * N128 + (size_t)s * HID))[lane];
        float p = q2.x * k2.x + q2.y * k2.y;
        p += __shfl_xor(p, 1);
        p += __shfl_xor(p, 2);
        p += __shfl_xor(p, 4);
        sc[l] = p * 0.25f;  // 1/sqrt(16)
    }
    float m = sc[0];
#pragma unroll
    for (int l = 1; l < L; ++l) m = fmaxf(m, sc[l]);
    float den = 0.f;
#pragma unroll
    for (int l = 0; l < L; ++l) { sc[l] = expf(sc[l] - m); den += sc[l]; }
    float inv = 1.0f / den;
    float mx = 0.f, my = 0.f;
#pragma unroll
    for (int l = 0; l < L; ++l) {
        float a = sc[l] * inv;
        mx = fmaf(a, v2[l].x, mx);
        my = fmaf(a, v2[l].y, my);
    }
    float* ap = aggout + (size_t)d * HID + lane * 2;
    atomicAdd(ap, nm * mx);
    atomicAdd(ap + 1, nm * my);
}

// ---------------- final: logits + log_softmax, one wave per row, lane = class ----------------
__global__ __launch_bounds__(256) void final_out(const float* __restrict__ xin,
                                                 const float* __restrict__ W2,
                                                 const float* __restrict__ b2,
                                                 float* __restrict__ out) {
    int wid = (blockIdx.x * 256 + threadIdx.x) >> 6;
    int lane = threadIdx.x & 63;
    if (wid >= NN) return;
    const float* xr = xin + (size_t)wid * HID;
    float acc = b2[lane];
#pragma unroll 8
    for (int i = 0; i < HID; ++i) {
        float xv = fmaxf(xr[i], 0.f);  // relu-on-load (x_all stored pre-activation)
        acc = fmaf(xv, W2[i * 64 + lane], acc);
    }
    float m = acc;
#pragma unroll
    for (int sft = 32; sft; sft >>= 1) m = fmaxf(m, __shfl_xor(m, sft));
    float e = expf(acc - m), den = e;
#pragma unroll
    for (int sft = 32; sft; sft >>= 1) den += __shfl_xor(den, sft);
    out[(size_t)wid * 64 + lane] = acc - m - logf(den);
}

extern "C" void kernel_launch(void* const* d_in, const int* in_sizes, int n_in,
                              void* d_out, int out_size, void* d_ws, size_t ws_size,
                              hipStream_t stream) {
    (void)in_sizes; (void)n_in; (void)out_size; (void)ws_size;
    const float* x  = (const float*)d_in[0];
    const int*   ei = (const int*)d_in[1];
    const float* W1 = (const float*)d_in[2];
    const float* b1 = (const float*)d_in[3];
    const float* Wq = (const float*)d_in[4];
    const float* bq = (const float*)d_in[5];
    const float* Wk = (const float*)d_in[6];
    const float* bk = (const float*)d_in[7];
    const float* Wv = (const float*)d_in[8];
    const float* bv = (const float*)d_in[9];
    const float* W2 = (const float*)d_in[10];
    const float* b2 = (const float*)d_in[11];
    float* out = (float*)d_out;

    float* ws  = (float*)d_ws;
    float* deg = ws;                                   // NN (padded to 16384)
    float* lvl0 = ws + 16384;                          // 4 levels x N128 (pre-activation)
    float* qn  = lvl0 + 4 * (size_t)N128;              // N128
    float* kn  = qn + N128;                            // 3 x N128
    float* vn  = kn + 3 * (size_t)N128;                // 3 x N128
    auto lvl = [&](int i) { return lvl0 + (size_t)i * N128; };

    hipMemsetAsync(deg, 0, NN * sizeof(float), stream);
    hipMemsetAsync(lvl(1), 0, 3 * (size_t)N128 * sizeof(float), stream);

    deg_count<<<(EE + 255) / 256, 256, 0, stream>>>(ei + EE, deg);
    make_dinv<<<(NN + 255) / 256, 256, 0, stream>>>(deg);

    {   // lvl0 = x @ W1 + b1 (stored pre-relu; consumers relu-on-load)
        GemmJobs jobs{};
        jobs.j[0] = {x, W1, b1, lvl(0)};
        dim3 g((NN + 63) / 64, 1);
        gemm128<false><<<g, 256, 0, stream>>>(jobs, NN);
    }

    const int total = EE + NN;
    const int eblocks = (total * 64 + 255) / 256;
    for (int l = 0; l < 3; ++l) {
        int L = l + 1;
        GemmJobs jobs{};
        jobs.j[0] = {lvl(L - 1), Wq + (size_t)l * HID * HID, bq + l * HID, qn};
        for (int lev = 0; lev < L; ++lev) {
            jobs.j[1 + lev]     = {lvl(lev), Wk + (size_t)l * HID * HID, bk + l * HID, kn + (size_t)lev * N128};
            jobs.j[1 + L + lev] = {lvl(lev), Wv + (size_t)l * HID * HID, bv + l * HID, vn + (size_t)lev * N128};
        }
        dim3 g((NN + 63) / 64, 2 * L + 1);
        gemm128<true><<<g, 256, 0, stream>>>(jobs, NN);

        if (L == 1) edge_attn<1><<<eblocks, 256, 0, stream>>>(ei, deg, qn, kn, vn, lvl(1), total);
        if (L == 2) edge_attn<2><<<eblocks, 256, 0, stream>>>(ei, deg, qn, kn, vn, lvl(2), total);
        if (L == 3) edge_attn<3><<<eblocks, 256, 0, stream>>>(ei, deg, qn, kn, vn, lvl(3), total);
    }

    final_out<<<(NN * 64 + 255) / 256, 256, 0, stream>>>(lvl(3), W2, b2, out);
}

// Round 2
// 368.962 us; speedup vs baseline: 1.7263x; 1.7263x over previous
//
#include <hip/hip_runtime.h>
#include <math.h>

#define NN 10000
#define EE 160000
#define HID 128
constexpr int N128 = NN * HID;
constexpr int KVSTRIDE = 768;  // 3 levels x (k:128 + v:128)

// ---------------- degree count (by dst) ----------------
__global__ __launch_bounds__(256) void cnt_count(const int* __restrict__ dst, int* __restrict__ cnt) {
    int e = blockIdx.x * 256 + threadIdx.x;
    if (e < EE) atomicAdd(&cnt[dst[e]], 1);
}

__global__ __launch_bounds__(256) void make_dinv(const int* __restrict__ cnt, float* __restrict__ dinv) {
    int i = blockIdx.x * 256 + threadIdx.x;
    if (i < NN) dinv[i] = rsqrtf((float)cnt[i] + 1.0f);  // +1 self-loop
}

// ---------------- single-block exclusive scan -> rowptr ----------------
__global__ __launch_bounds__(256) void scan_rowptr(const int* __restrict__ cnt, int* __restrict__ rowptr) {
    __shared__ int part[256];
    const int PER = (NN + 255) / 256;  // 40
    int t = threadIdx.x;
    int base = t * PER;
    int sum = 0;
    for (int i = 0; i < PER; ++i) { int idx = base + i; if (idx < NN) sum += cnt[idx]; }
    part[t] = sum;
    __syncthreads();
    for (int ofs = 1; ofs < 256; ofs <<= 1) {
        int v = (t >= ofs) ? part[t - ofs] : 0;
        __syncthreads();
        part[t] += v;
        __syncthreads();
    }
    int run = (t > 0) ? part[t - 1] : 0;
    for (int i = 0; i < PER; ++i) {
        int idx = base + i;
        if (idx <= NN) rowptr[idx] = run;
        if (idx < NN) run += cnt[idx];
    }
}

__global__ __launch_bounds__(256) void scatter_edges(const int* __restrict__ ei,
                                                     const int* __restrict__ rowptr,
                                                     int* __restrict__ fill,
                                                     int* __restrict__ esorted) {
    int e = blockIdx.x * 256 + threadIdx.x;
    if (e < EE) {
        int s = ei[e], d = ei[EE + e];
        int pos = rowptr[d] + atomicAdd(&fill[d], 1);
        esorted[pos] = s;
    }
}

// ---------------- fp32 GEMM: out[n][o] = sum_i act(in[n][i]) * W[i][o] + b[o] ----------------
struct GemmJob { const float* in; const float* W; const float* bias; float* out; int ldo; };
struct GemmJobs { GemmJob j[7]; };

template<bool RELU_IN>
__global__ __launch_bounds__(256) void gemm128(GemmJobs jobs, int nrows) {
    const GemmJob jb = jobs.j[blockIdx.y];
    __shared__ float Xl[64][HID];
    __shared__ float Wl[32][HID];
    __shared__ float bl[HID];
    const int t = threadIdx.x;
    const int row0 = blockIdx.x * 64;

    for (int i = t; i < 2048; i += 256) {
        int r = i >> 5, c4 = i & 31;
        float4 xv = make_float4(0.f, 0.f, 0.f, 0.f);
        int rr = row0 + r;
        if (rr < nrows) xv = ((const float4*)(jb.in + (size_t)rr * HID))[c4];
        if (RELU_IN) {
            xv.x = fmaxf(xv.x, 0.f); xv.y = fmaxf(xv.y, 0.f);
            xv.z = fmaxf(xv.z, 0.f); xv.w = fmaxf(xv.w, 0.f);
        }
        *((float4*)&Xl[r][c4 * 4]) = xv;
    }
    if (t < HID) bl[t] = jb.bias[t];

    const int tr = t >> 4, tc = t & 15;
    float acc[4][8];
#pragma unroll
    for (int j = 0; j < 4; ++j)
#pragma unroll
        for (int c = 0; c < 8; ++c) acc[j][c] = 0.f;

    for (int ks = 0; ks < 4; ++ks) {
        __syncthreads();
        for (int i = t; i < 1024; i += 256) {
            int r = i >> 5, c4 = i & 31;
            *((float4*)&Wl[r][c4 * 4]) = ((const float4*)(jb.W + (size_t)(ks * 32 + r) * HID))[c4];
        }
        __syncthreads();
#pragma unroll
        for (int kk = 0; kk < 32; ++kk) {
            float xv[4];
#pragma unroll
            for (int j = 0; j < 4; ++j) xv[j] = Xl[tr * 4 + j][ks * 32 + kk];
            float4 w0 = *((const float4*)&Wl[kk][tc * 8]);
            float4 w1 = *((const float4*)&Wl[kk][tc * 8 + 4]);
            float w[8] = {w0.x, w0.y, w0.z, w0.w, w1.x, w1.y, w1.z, w1.w};
#pragma unroll
            for (int j = 0; j < 4; ++j)
#pragma unroll
                for (int c = 0; c < 8; ++c)
                    acc[j][c] = fmaf(xv[j], w[c], acc[j][c]);
        }
    }

#pragma unroll
    for (int j = 0; j < 4; ++j) {
        int rr = row0 + tr * 4 + j;
        if (rr < nrows) {
            float4 o0, o1;
            o0.x = acc[j][0] + bl[tc * 8 + 0];
            o0.y = acc[j][1] + bl[tc * 8 + 1];
            o0.z = acc[j][2] + bl[tc * 8 + 2];
            o0.w = acc[j][3] + bl[tc * 8 + 3];
            o1.x = acc[j][4] + bl[tc * 8 + 4];
            o1.y = acc[j][5] + bl[tc * 8 + 5];
            o1.z = acc[j][6] + bl[tc * 8 + 6];
            o1.w = acc[j][7] + bl[tc * 8 + 7];
            float4* op = (float4*)(jb.out + (size_t)rr * jb.ldo);
            op[tc * 2] = o0;
            op[tc * 2 + 1] = o1;
        }
    }
}

// ---------------- node-centric attention: one wave per dst node ----------------
// lane owns channels {2*lane, 2*lane+1}; head = lane>>3; score reduce = shfl_xor 1,2,4
template<int L>
__global__ __launch_bounds__(256) void node_attn(
    const int* __restrict__ rowptr, const int* __restrict__ esorted,
    const float* __restrict__ dinv,
    const float* __restrict__ qn, const float* __restrict__ kv,
    float* __restrict__ outv) {
    int d = (blockIdx.x * 256 + threadIdx.x) >> 6;
    int lane = threadIdx.x & 63;
    if (d >= NN) return;
    int i0 = rowptr[d], i1 = rowptr[d + 1];
    int nE = i1 - i0 + 1;  // real in-edges + self-loop (processed last)
    float dvd = dinv[d];
    float2 q2 = ((const float2*)(qn + (size_t)d * HID))[lane];
    float ax = 0.f, ay = 0.f;

    int sCur = (nE > 1) ? esorted[i0] : d;
    float dvs = dinv[sCur];
    float2 k2[L], v2[L];
    {
        const float2* bp = (const float2*)(kv + (size_t)sCur * KVSTRIDE);
#pragma unroll
        for (int l = 0; l < L; ++l) { k2[l] = bp[l * 128 + lane]; v2[l] = bp[l * 128 + 64 + lane]; }
    }

    for (int j = 0; j < nE; ++j) {
        // prefetch next edge
        int sNext = (j + 2 <= nE - 1) ? esorted[i0 + j + 1] : d;
        float ndvs = dinv[sNext];
        float2 nk[L], nv[L];
        if (j + 1 < nE) {
            const float2* np = (const float2*)(kv + (size_t)sNext * KVSTRIDE);
#pragma unroll
            for (int l = 0; l < L; ++l) { nk[l] = np[l * 128 + lane]; nv[l] = np[l * 128 + 64 + lane]; }
        }
        // compute current
        float sc[L];
#pragma unroll
        for (int l = 0; l < L; ++l) {
            float p = q2.x * k2[l].x + q2.y * k2[l].y;
            p += __shfl_xor(p, 1);
            p += __shfl_xor(p, 2);
            p += __shfl_xor(p, 4);
            sc[l] = p * 0.25f;  // 1/sqrt(16)
        }
        float m = sc[0];
#pragma unroll
        for (int l = 1; l < L; ++l) m = fmaxf(m, sc[l]);
        float den = 0.f;
#pragma unroll
        for (int l = 0; l < L; ++l) { sc[l] = __expf(sc[l] - m); den += sc[l]; }
        float w = dvd * dvs / den;
#pragma unroll
        for (int l = 0; l < L; ++l) {
            ax = fmaf(sc[l] * w, v2[l].x, ax);
            ay = fmaf(sc[l] * w, v2[l].y, ay);
        }
        // shift pipeline
#pragma unroll
        for (int l = 0; l < L; ++l) { k2[l] = nk[l]; v2[l] = nv[l]; }
        dvs = ndvs;
    }
    ((float2*)(outv + (size_t)d * HID))[lane] = make_float2(ax, ay);
}

// ---------------- final: logits + log_softmax ----------------
__global__ __launch_bounds__(256) void final_out(const float* __restrict__ xin,
                                                 const float* __restrict__ W2,
                                                 const float* __restrict__ b2,
                                                 float* __restrict__ out) {
    int wid = (blockIdx.x * 256 + threadIdx.x) >> 6;
    int lane = threadIdx.x & 63;
    if (wid >= NN) return;
    const float* xr = xin + (size_t)wid * HID;
    float acc = b2[lane];
#pragma unroll 8
    for (int i = 0; i < HID; ++i) {
        float xv = fmaxf(xr[i], 0.f);  // relu-on-load (levels stored pre-activation)
        acc = fmaf(xv, W2[i * 64 + lane], acc);
    }
    float m = acc;
#pragma unroll
    for (int sft = 32; sft; sft >>= 1) m = fmaxf(m, __shfl_xor(m, sft));
    float e = __expf(acc - m), den = e;
#pragma unroll
    for (int sft = 32; sft; sft >>= 1) den += __shfl_xor(den, sft);
    out[(size_t)wid * 64 + lane] = acc - m - logf(den);
}

extern "C" void kernel_launch(void* const* d_in, const int* in_sizes, int n_in,
                              void* d_out, int out_size, void* d_ws, size_t ws_size,
                              hipStream_t stream) {
    (void)in_sizes; (void)n_in; (void)out_size; (void)ws_size;
    const float* x  = (const float*)d_in[0];
    const int*   ei = (const int*)d_in[1];
    const float* W1 = (const float*)d_in[2];
    const float* b1 = (const float*)d_in[3];
    const float* Wq = (const float*)d_in[4];
    const float* bq = (const float*)d_in[5];
    const float* Wk = (const float*)d_in[6];
    const float* bk = (const float*)d_in[7];
    const float* Wv = (const float*)d_in[8];
    const float* bv = (const float*)d_in[9];
    const float* W2 = (const float*)d_in[10];
    const float* b2 = (const float*)d_in[11];
    float* out = (float*)d_out;

    // workspace layout (4-byte words)
    int*   cnt     = (int*)d_ws;                 // 16384
    int*   fill    = cnt + 16384;                // 16384
    int*   rowptr  = fill + 16384;               // 16384 (NN+1)
    int*   esorted = rowptr + 16384;             // EE (pad 163840)
    float* dinv    = (float*)(esorted + 163840); // 16384
    float* lvl0    = dinv + 16384;               // 4 x N128 (pre-activation)
    float* qn      = lvl0 + 4 * (size_t)N128;    // N128
    float* kvb     = qn + N128;                  // NN x 768
    auto lvl = [&](int i) { return lvl0 + (size_t)i * N128; };

    hipMemsetAsync(cnt, 0, 2 * 16384 * sizeof(int), stream);  // cnt + fill

    cnt_count<<<(EE + 255) / 256, 256, 0, stream>>>(ei + EE, cnt);
    make_dinv<<<(NN + 255) / 256, 256, 0, stream>>>(cnt, dinv);
    scan_rowptr<<<1, 256, 0, stream>>>(cnt, rowptr);
    scatter_edges<<<(EE + 255) / 256, 256, 0, stream>>>(ei, rowptr, fill, esorted);

    {   // lvl0 = x @ W1 + b1 (stored pre-relu; consumers relu-on-load)
        GemmJobs jobs{};
        jobs.j[0] = {x, W1, b1, lvl(0), HID};
        dim3 g((NN + 63) / 64, 1);
        gemm128<false><<<g, 256, 0, stream>>>(jobs, NN);
    }

    const int nblocks = (NN * 64 + 255) / 256;
    for (int l = 0; l < 3; ++l) {
        int L = l + 1;
        GemmJobs jobs{};
        jobs.j[0] = {lvl(L - 1), Wq + (size_t)l * HID * HID, bq + l * HID, qn, HID};
        for (int lev = 0; lev < L; ++lev) {
            jobs.j[1 + lev]     = {lvl(lev), Wk + (size_t)l * HID * HID, bk + l * HID, kvb + lev * 256, KVSTRIDE};
            jobs.j[1 + L + lev] = {lvl(lev), Wv + (size_t)l * HID * HID, bv + l * HID, kvb + lev * 256 + 128, KVSTRIDE};
        }
        dim3 g((NN + 63) / 64, 2 * L + 1);
        gemm128<true><<<g, 256, 0, stream>>>(jobs, NN);

        if (L == 1) node_attn<1><<<nblocks, 256, 0, stream>>>(rowptr, esorted, dinv, qn, kvb, lvl(1));
        if (L == 2) node_attn<2><<<nblocks, 256, 0, stream>>>(rowptr, esorted, dinv, qn, kvb, lvl(2));
        if (L == 3) node_attn<3><<<nblocks, 256, 0, stream>>>(rowptr, esorted, dinv, qn, kvb, lvl(3));
    }

    final_out<<<(NN * 64 + 255) / 256, 256, 0, stream>>>(lvl(3), W2, b2, out);
}

// Round 3
// 317.905 us; speedup vs baseline: 2.0035x; 1.1606x over previous
//
#include <hip/hip_runtime.h>
#include <hip/hip_fp16.h>
#include <math.h>

#define NN 10000
#define EE 160000
#define HID 128
constexpr int N128 = NN * HID;
constexpr int KVH = 768;  // halves per node in kv buffer: 3 levels x (k:128 + v:128)

// ---------------- degree count (by dst) ----------------
__global__ __launch_bounds__(256) void cnt_count(const int* __restrict__ dst, int* __restrict__ cnt) {
    int e = blockIdx.x * 256 + threadIdx.x;
    if (e < EE) atomicAdd(&cnt[dst[e]], 1);
}

__global__ __launch_bounds__(256) void make_dinv(const int* __restrict__ cnt, float* __restrict__ dinv) {
    int i = blockIdx.x * 256 + threadIdx.x;
    if (i < NN) dinv[i] = rsqrtf((float)cnt[i] + 1.0f);  // +1 self-loop
}

// ---------------- single-block exclusive scan -> rowptr ----------------
__global__ __launch_bounds__(256) void scan_rowptr(const int* __restrict__ cnt, int* __restrict__ rowptr) {
    __shared__ int part[256];
    const int PER = (NN + 255) / 256;  // 40
    int t = threadIdx.x;
    int base = t * PER;
    int sum = 0;
    for (int i = 0; i < PER; ++i) { int idx = base + i; if (idx < NN) sum += cnt[idx]; }
    part[t] = sum;
    __syncthreads();
    for (int ofs = 1; ofs < 256; ofs <<= 1) {
        int v = (t >= ofs) ? part[t - ofs] : 0;
        __syncthreads();
        part[t] += v;
        __syncthreads();
    }
    int run = (t > 0) ? part[t - 1] : 0;
    for (int i = 0; i < PER; ++i) {
        int idx = base + i;
        if (idx <= NN) rowptr[idx] = run;
        if (idx < NN) run += cnt[idx];
    }
}

__global__ __launch_bounds__(256) void scatter_edges(const int* __restrict__ ei,
                                                     const int* __restrict__ rowptr,
                                                     int* __restrict__ fill,
                                                     int* __restrict__ esorted) {
    int e = blockIdx.x * 256 + threadIdx.x;
    if (e < EE) {
        int s = ei[e], d = ei[EE + e];
        int pos = rowptr[d] + atomicAdd(&fill[d], 1);
        esorted[pos] = s;
    }
}

// ---------------- fp32 GEMM (multi-job), optional fp16 output + per-row bias scale ----------------
struct GemmJob {
    const float* in; const float* W; const float* bias; const float* rowscale;
    float* out; int ldo; int outHalf;
};
struct GemmJobs { GemmJob j[7]; };

template<bool RELU_IN>
__global__ __launch_bounds__(256) void gemm128(GemmJobs jobs, int nrows) {
    const GemmJob jb = jobs.j[blockIdx.y];
    __shared__ float Xl[64][HID];
    __shared__ float Wl[32][HID];
    __shared__ float bl[HID];
    const int t = threadIdx.x;
    const int row0 = blockIdx.x * 64;

    for (int i = t; i < 2048; i += 256) {
        int r = i >> 5, c4 = i & 31;
        float4 xv = make_float4(0.f, 0.f, 0.f, 0.f);
        int rr = row0 + r;
        if (rr < nrows) xv = ((const float4*)(jb.in + (size_t)rr * HID))[c4];
        if (RELU_IN) {
            xv.x = fmaxf(xv.x, 0.f); xv.y = fmaxf(xv.y, 0.f);
            xv.z = fmaxf(xv.z, 0.f); xv.w = fmaxf(xv.w, 0.f);
        }
        *((float4*)&Xl[r][c4 * 4]) = xv;
    }
    if (t < HID) bl[t] = jb.bias[t];

    const int tr = t >> 4, tc = t & 15;
    float acc[4][8];
#pragma unroll
    for (int j = 0; j < 4; ++j)
#pragma unroll
        for (int c = 0; c < 8; ++c) acc[j][c] = 0.f;

    for (int ks = 0; ks < 4; ++ks) {
        __syncthreads();
        for (int i = t; i < 1024; i += 256) {
            int r = i >> 5, c4 = i & 31;
            *((float4*)&Wl[r][c4 * 4]) = ((const float4*)(jb.W + (size_t)(ks * 32 + r) * HID))[c4];
        }
        __syncthreads();
#pragma unroll
        for (int kk = 0; kk < 32; ++kk) {
            float xv[4];
#pragma unroll
            for (int j = 0; j < 4; ++j) xv[j] = Xl[tr * 4 + j][ks * 32 + kk];
            float4 w0 = *((const float4*)&Wl[kk][tc * 8]);
            float4 w1 = *((const float4*)&Wl[kk][tc * 8 + 4]);
            float w[8] = {w0.x, w0.y, w0.z, w0.w, w1.x, w1.y, w1.z, w1.w};
#pragma unroll
            for (int j = 0; j < 4; ++j)
#pragma unroll
                for (int c = 0; c < 8; ++c)
                    acc[j][c] = fmaf(xv[j], w[c], acc[j][c]);
        }
    }

#pragma unroll
    for (int j = 0; j < 4; ++j) {
        int rr = row0 + tr * 4 + j;
        if (rr < nrows) {
            float rs = jb.rowscale ? jb.rowscale[rr] : 1.0f;
            float o[8];
#pragma unroll
            for (int c = 0; c < 8; ++c) o[c] = acc[j][c] + rs * bl[tc * 8 + c];
            if (jb.outHalf) {
                union { __half2 h2[4]; float4 f4; } u;
#pragma unroll
                for (int c = 0; c < 4; ++c) u.h2[c] = __floats2half2_rn(o[2 * c], o[2 * c + 1]);
                __half* op = (__half*)jb.out + (size_t)rr * jb.ldo;
                *((float4*)(op + tc * 8)) = u.f4;
            } else {
                float4 o0 = make_float4(o[0], o[1], o[2], o[3]);
                float4 o1 = make_float4(o[4], o[5], o[6], o[7]);
                float4* op = (float4*)(jb.out + (size_t)rr * jb.ldo);
                op[tc * 2] = o0;
                op[tc * 2 + 1] = o1;
            }
        }
    }
}

// ---------------- relu + fp16 convert: h16 = half(relu(lvl0)) ----------------
__global__ __launch_bounds__(256) void relu_h16(const float* __restrict__ xin, __half* __restrict__ h16) {
    int i = blockIdx.x * 256 + threadIdx.x;  // half2 index
    if (i < N128 / 2) {
        float2 f = ((const float2*)xin)[i];
        ((__half2*)h16)[i] = __floats2half2_rn(fmaxf(f.x, 0.f), fmaxf(f.y, 0.f));
    }
}

// ---------------- layer-1 GCN aggregation: S[d] = dvd * sum dvs*relu(h)[s]; srow[d] = dvd*sum dvs ----------------
__global__ __launch_bounds__(256) void sgather(
    const int* __restrict__ rowptr, const int* __restrict__ esorted,
    const float* __restrict__ dinv, const __half* __restrict__ h16,
    float* __restrict__ S, float* __restrict__ srow) {
    int d = (blockIdx.x * 256 + threadIdx.x) >> 6;
    int lane = threadIdx.x & 63;
    if (d >= NN) return;
    int i0 = rowptr[d], i1 = rowptr[d + 1];
    int nE = i1 - i0 + 1;  // + self-loop (last)
    float dvd = dinv[d];
    float ax = 0.f, ay = 0.f, ssum = 0.f;
    for (int j = 0; j < nE; ++j) {
        int s = (j < nE - 1) ? esorted[i0 + j] : d;
        float dvs = dinv[s];
        float2 f = __half22float2(((const __half2*)h16)[(size_t)s * 64 + lane]);
        ax = fmaf(dvs, f.x, ax);
        ay = fmaf(dvs, f.y, ay);
        ssum += dvs;
    }
    ((float2*)(S + (size_t)d * HID))[lane] = make_float2(dvd * ax, dvd * ay);
    if (lane == 0) srow[d] = dvd * ssum;
}

// ---------------- node-centric attention (fp16 kv): one wave per dst node ----------------
template<int L>
__global__ __launch_bounds__(256) void node_attn(
    const int* __restrict__ rowptr, const int* __restrict__ esorted,
    const float* __restrict__ dinv,
    const float* __restrict__ qn, const __half* __restrict__ kv,
    float* __restrict__ outv) {
    int d = (blockIdx.x * 256 + threadIdx.x) >> 6;
    int lane = threadIdx.x & 63;
    if (d >= NN) return;
    int i0 = rowptr[d], i1 = rowptr[d + 1];
    int nE = i1 - i0 + 1;
    float dvd = dinv[d];
    float2 q2 = ((const float2*)(qn + (size_t)d * HID))[lane];
    float ax = 0.f, ay = 0.f;

    int sCur = (nE > 1) ? esorted[i0] : d;
    float dvs = dinv[sCur];
    float2 k2[L], v2[L];
    {
        const __half2* bp = (const __half2*)(kv + (size_t)sCur * KVH);
#pragma unroll
        for (int l = 0; l < L; ++l) {
            k2[l] = __half22float2(bp[l * 128 + lane]);
            v2[l] = __half22float2(bp[l * 128 + 64 + lane]);
        }
    }

    for (int j = 0; j < nE; ++j) {
        int sNext = (j + 2 <= nE - 1) ? esorted[i0 + j + 1] : d;
        float ndvs = dinv[sNext];
        float2 nk[L], nv[L];
        if (j + 1 < nE) {
            const __half2* np = (const __half2*)(kv + (size_t)sNext * KVH);
#pragma unroll
            for (int l = 0; l < L; ++l) {
                nk[l] = __half22float2(np[l * 128 + lane]);
                nv[l] = __half22float2(np[l * 128 + 64 + lane]);
            }
        }
        float sc[L];
#pragma unroll
        for (int l = 0; l < L; ++l) {
            float p = q2.x * k2[l].x + q2.y * k2[l].y;
            p += __shfl_xor(p, 1);
            p += __shfl_xor(p, 2);
            p += __shfl_xor(p, 4);
            sc[l] = p * 0.25f;  // 1/sqrt(16)
        }
        float m = sc[0];
#pragma unroll
        for (int l = 1; l < L; ++l) m = fmaxf(m, sc[l]);
        float den = 0.f;
#pragma unroll
        for (int l = 0; l < L; ++l) { sc[l] = __expf(sc[l] - m); den += sc[l]; }
        float w = dvd * dvs / den;
#pragma unroll
        for (int l = 0; l < L; ++l) {
            ax = fmaf(sc[l] * w, v2[l].x, ax);
            ay = fmaf(sc[l] * w, v2[l].y, ay);
        }
#pragma unroll
        for (int l = 0; l < L; ++l) { k2[l] = nk[l]; v2[l] = nv[l]; }
        dvs = ndvs;
    }
    ((float2*)(outv + (size_t)d * HID))[lane] = make_float2(ax, ay);
}

// ---------------- final: logits + log_softmax ----------------
__global__ __launch_bounds__(256) void final_out(const float* __restrict__ xin,
                                                 const float* __restrict__ W2,
                                                 const float* __restrict__ b2,
                                                 float* __restrict__ out) {
    int wid = (blockIdx.x * 256 + threadIdx.x) >> 6;
    int lane = threadIdx.x & 63;
    if (wid >= NN) return;
    const float* xr = xin + (size_t)wid * HID;
    float acc = b2[lane];
#pragma unroll 8
    for (int i = 0; i < HID; ++i) {
        float xv = fmaxf(xr[i], 0.f);  // relu-on-load (levels stored pre-activation)
        acc = fmaf(xv, W2[i * 64 + lane], acc);
    }
    float m = acc;
#pragma unroll
    for (int sft = 32; sft; sft >>= 1) m = fmaxf(m, __shfl_xor(m, sft));
    float e = __expf(acc - m), den = e;
#pragma unroll
    for (int sft = 32; sft; sft >>= 1) den += __shfl_xor(den, sft);
    out[(size_t)wid * 64 + lane] = acc - m - logf(den);
}

extern "C" void kernel_launch(void* const* d_in, const int* in_sizes, int n_in,
                              void* d_out, int out_size, void* d_ws, size_t ws_size,
                              hipStream_t stream) {
    (void)in_sizes; (void)n_in; (void)out_size; (void)ws_size;
    const float* x  = (const float*)d_in[0];
    const int*   ei = (const int*)d_in[1];
    const float* W1 = (const float*)d_in[2];
    const float* b1 = (const float*)d_in[3];
    const float* Wq = (const float*)d_in[4];
    const float* bq = (const float*)d_in[5];
    const float* Wk = (const float*)d_in[6];
    const float* bk = (const float*)d_in[7];
    const float* Wv = (const float*)d_in[8];
    const float* bv = (const float*)d_in[9];
    const float* W2 = (const float*)d_in[10];
    const float* b2 = (const float*)d_in[11];
    float* out = (float*)d_out;

    // workspace layout (word = 4B)
    int*    cnt     = (int*)d_ws;                  // 16384
    int*    fill    = cnt + 16384;                 // 16384
    int*    rowptr  = fill + 16384;                // 16384 (NN+1)
    int*    esorted = rowptr + 16384;              // 163840
    float*  dinv    = (float*)(esorted + 163840);  // 16384
    float*  srow    = dinv + 16384;                // 16384
    float*  lvl0    = srow + 16384;                // 4 x N128 (pre-activation, fp32)
    float*  qn      = lvl0 + 4 * (size_t)N128;     // N128 (doubles as S for layer 1)
    __half* h16     = (__half*)(qn + N128);        // N128 halves (relu(lvl0))
    __half* kvb     = h16 + ((N128 + 8192) & ~8191); // NN x 768 halves
    auto lvl = [&](int i) { return lvl0 + (size_t)i * N128; };

    hipMemsetAsync(cnt, 0, 2 * 16384 * sizeof(int), stream);  // cnt + fill

    cnt_count<<<(EE + 255) / 256, 256, 0, stream>>>(ei + EE, cnt);
    make_dinv<<<(NN + 255) / 256, 256, 0, stream>>>(cnt, dinv);
    scan_rowptr<<<1, 256, 0, stream>>>(cnt, rowptr);
    scatter_edges<<<(EE + 255) / 256, 256, 0, stream>>>(ei, rowptr, fill, esorted);

    const int gemmx = (NN + 63) / 64;
    {   // lvl0 = x @ W1 + b1 (pre-relu)
        GemmJobs jobs{};
        jobs.j[0] = {x, W1, b1, nullptr, lvl(0), HID, 0};
        gemm128<false><<<dim3(gemmx, 1), 256, 0, stream>>>(jobs, NN);
    }
    relu_h16<<<(N128 / 2 + 255) / 256, 256, 0, stream>>>(lvl(0), h16);

    const int nblocks = (NN * 64 + 255) / 256;

    // ---- layer 1 (L=1: softmax over 1 level == identity -> pure GCN) ----
    sgather<<<nblocks, 256, 0, stream>>>(rowptr, esorted, dinv, h16, qn /*=S*/, srow);
    {   // lvl1 = S @ Wv1 + srow*bv1  (input already aggregated+relu'd: no RELU_IN)
        GemmJobs jobs{};
        jobs.j[0] = {qn, Wv, bv, srow, lvl(1), HID, 0};
        gemm128<false><<<dim3(gemmx, 1), 256, 0, stream>>>(jobs, NN);
    }

    // ---- layers 2,3 (real attention, fp16 kv gather) ----
    for (int l = 1; l < 3; ++l) {
        int L = l + 1;
        GemmJobs jobs{};
        jobs.j[0] = {lvl(L - 1), Wq + (size_t)l * HID * HID, bq + l * HID, nullptr, qn, HID, 0};
        for (int lev = 0; lev < L; ++lev) {
            jobs.j[1 + lev]     = {lvl(lev), Wk + (size_t)l * HID * HID, bk + l * HID, nullptr,
                                   (float*)(kvb + lev * 256), KVH, 1};
            jobs.j[1 + L + lev] = {lvl(lev), Wv + (size_t)l * HID * HID, bv + l * HID, nullptr,
                                   (float*)(kvb + lev * 256 + 128), KVH, 1};
        }
        gemm128<true><<<dim3(gemmx, 2 * L + 1), 256, 0, stream>>>(jobs, NN);

        if (L == 2) node_attn<2><<<nblocks, 256, 0, stream>>>(rowptr, esorted, dinv, qn, kvb, lvl(2));
        if (L == 3) node_attn<3><<<nblocks, 256, 0, stream>>>(rowptr, esorted, dinv, qn, kvb, lvl(3));
    }

    final_out<<<(NN * 64 + 255) / 256, 256, 0, stream>>>(lvl(3), W2, b2, out);
}

// Round 4
// 230.634 us; speedup vs baseline: 2.7616x; 1.3784x over previous
//
#include <hip/hip_runtime.h>
#include <hip/hip_fp16.h>
#include <math.h>

#define NN 10000
#define EE 160000
#define HID 128
constexpr int N128 = NN * HID;
constexpr int KVH = 768;  // halves per node in kv buffer: 3 levels x (k:128 + v:128)

typedef _Float16 f16;
typedef f16 half8 __attribute__((ext_vector_type(8)));
typedef float f32x4 __attribute__((ext_vector_type(4)));

// ---------------- degree count (by dst) ----------------
__global__ __launch_bounds__(256) void cnt_count(const int* __restrict__ dst, int* __restrict__ cnt) {
    int e = blockIdx.x * 256 + threadIdx.x;
    if (e < EE) atomicAdd(&cnt[dst[e]], 1);
}

__global__ __launch_bounds__(256) void make_dinv(const int* __restrict__ cnt, float* __restrict__ dinv) {
    int i = blockIdx.x * 256 + threadIdx.x;
    if (i < NN) dinv[i] = rsqrtf((float)cnt[i] + 1.0f);  // +1 self-loop
}

// ---------------- single-block exclusive scan -> rowptr ----------------
__global__ __launch_bounds__(256) void scan_rowptr(const int* __restrict__ cnt, int* __restrict__ rowptr) {
    __shared__ int part[256];
    const int PER = (NN + 255) / 256;  // 40
    int t = threadIdx.x;
    int base = t * PER;
    int sum = 0;
    for (int i = 0; i < PER; ++i) { int idx = base + i; if (idx < NN) sum += cnt[idx]; }
    part[t] = sum;
    __syncthreads();
    for (int ofs = 1; ofs < 256; ofs <<= 1) {
        int v = (t >= ofs) ? part[t - ofs] : 0;
        __syncthreads();
        part[t] += v;
        __syncthreads();
    }
    int run = (t > 0) ? part[t - 1] : 0;
    for (int i = 0; i < PER; ++i) {
        int idx = base + i;
        if (idx <= NN) rowptr[idx] = run;
        if (idx < NN) run += cnt[idx];
    }
}

__global__ __launch_bounds__(256) void scatter_edges(const int* __restrict__ ei,
                                                     const int* __restrict__ rowptr,
                                                     int* __restrict__ fill,
                                                     int* __restrict__ esorted) {
    int e = blockIdx.x * 256 + threadIdx.x;
    if (e < EE) {
        int s = ei[e], d = ei[EE + e];
        int pos = rowptr[d] + atomicAdd(&fill[d], 1);
        esorted[pos] = s;
    }
}

// ---------------- weight prep: Wt[mat][oc][k] = fp16(W[k][oc]), 10 matrices ----------------
__global__ __launch_bounds__(256) void wprep(const float* __restrict__ W1, const float* __restrict__ Wq,
                                             const float* __restrict__ Wk, const float* __restrict__ Wv,
                                             f16* __restrict__ Wt) {
    int b = blockIdx.x;  // 0=W1, 1..3=Wq[l], 4..6=Wk[l], 7..9=Wv[l]
    const float* src = (b == 0) ? W1
                     : (b < 4)  ? Wq + (size_t)(b - 1) * 16384
                     : (b < 7)  ? Wk + (size_t)(b - 4) * 16384
                                : Wv + (size_t)(b - 7) * 16384;
    f16* dst = Wt + (size_t)b * 16384;
    int t = threadIdx.x;
    int oc = t >> 1;
    int k0 = (t & 1) * 64;
    for (int kk = 0; kk < 64; ++kk) {
        int k = k0 + kk;
        dst[oc * 128 + k] = (f16)src[k * 128 + oc];
    }
}

// ---------------- x -> fp16 ----------------
__global__ __launch_bounds__(256) void tohalf(const float* __restrict__ in, __half* __restrict__ outh) {
    int i = blockIdx.x * 256 + threadIdx.x;
    if (i < N128 / 2) {
        float2 f = ((const float2*)in)[i];
        ((__half2*)outh)[i] = __floats2half2_rn(f.x, f.y);
    }
}

// ---------------- MFMA GEMM: out[n][oc] = sum_k in[n][k] * W[k][oc] + (rs*)bias[oc] ----------------
// in: fp16 row-major [nrows][128]; Wt: fp16 [oc][k] (transposed); mode 0=f32, 1=f16+relu, 2=f16 raw
struct GJob { const f16* in; const f16* Wt; const float* bias; const float* rowscale; void* out; int ldo; int mode; };
struct GJobs { GJob j[7]; };

__global__ __launch_bounds__(256) void gemm_mfma(GJobs jobs, int nrows) {
    const GJob jb = jobs.j[blockIdx.y];
    __shared__ f16 Xl[64 * 128];
    __shared__ f16 Wl[128 * 128];
    const int t = threadIdx.x;
    const int row0 = blockIdx.x * 64;

    half8 zero8;
#pragma unroll
    for (int z = 0; z < 8; ++z) zero8[z] = (f16)0.f;

    // stage X tile: 64 rows x 16 chunks(16B), swizzled byte ^= (row&7)<<4
#pragma unroll
    for (int it = 0; it < 4; ++it) {
        int idx = t + it * 256;
        int r = idx >> 4, c = idx & 15;
        int gr = row0 + r;
        half8 v = zero8;
        if (gr < nrows) v = *(const half8*)(jb.in + (size_t)gr * 128 + c * 8);
        *(half8*)((char*)Xl + r * 256 + ((c * 16) ^ ((r & 7) << 4))) = v;
    }
    // stage Wt: 128 rows x 16 chunks
#pragma unroll
    for (int it = 0; it < 8; ++it) {
        int idx = t + it * 256;
        int r = idx >> 4, c = idx & 15;
        half8 v = *(const half8*)(jb.Wt + (size_t)r * 128 + c * 8);
        *(half8*)((char*)Wl + r * 256 + ((c * 16) ^ ((r & 7) << 4))) = v;
    }
    __syncthreads();

    const int w = t >> 6, l = t & 63;
    const int lr = l & 15;          // A row / B col / D col within tile
    const int lk = l >> 4;          // k-group

    f32x4 acc[8];
#pragma unroll
    for (int tn = 0; tn < 8; ++tn)
#pragma unroll
        for (int i = 0; i < 4; ++i) acc[tn][i] = 0.f;

    const int arow = w * 16 + lr;
    const int axor = (arow & 7) << 4;
    const int bxor = (lr & 7) << 4;  // oc = tn*16+lr -> oc&7 == lr&7

#pragma unroll
    for (int ks = 0; ks < 4; ++ks) {
        int koff = (ks * 4 + lk) * 16;  // byte offset of 16B chunk along k
        half8 a = *(const half8*)((const char*)Xl + arow * 256 + (koff ^ axor));
#pragma unroll
        for (int tn = 0; tn < 8; ++tn) {
            int oc = tn * 16 + lr;
            half8 b = *(const half8*)((const char*)Wl + oc * 256 + (koff ^ bxor));
            acc[tn] = __builtin_amdgcn_mfma_f32_16x16x32_f16(a, b, acc[tn], 0, 0, 0);
        }
    }

    // epilogue: D[row=(l>>4)*4+i][col=lr] per tile
    const int rbase = row0 + w * 16 + (lk << 2);
    float brs[4];
#pragma unroll
    for (int i = 0; i < 4; ++i)
        brs[i] = jb.rowscale ? ((rbase + i < nrows) ? jb.rowscale[rbase + i] : 0.f) : 1.0f;
    float bsv[8];
#pragma unroll
    for (int tn = 0; tn < 8; ++tn) bsv[tn] = jb.bias[tn * 16 + lr];

    if (jb.mode == 0) {
        float* op = (float*)jb.out;
#pragma unroll
        for (int tn = 0; tn < 8; ++tn)
#pragma unroll
            for (int i = 0; i < 4; ++i) {
                int gr = rbase + i;
                if (gr < nrows) op[(size_t)gr * jb.ldo + tn * 16 + lr] = acc[tn][i] + brs[i] * bsv[tn];
            }
    } else if (jb.mode == 1) {
        f16* op = (f16*)jb.out;
#pragma unroll
        for (int tn = 0; tn < 8; ++tn)
#pragma unroll
            for (int i = 0; i < 4; ++i) {
                int gr = rbase + i;
                if (gr < nrows) op[(size_t)gr * jb.ldo + tn * 16 + lr] = (f16)fmaxf(acc[tn][i] + brs[i] * bsv[tn], 0.f);
            }
    } else {
        f16* op = (f16*)jb.out;
#pragma unroll
        for (int tn = 0; tn < 8; ++tn)
#pragma unroll
            for (int i = 0; i < 4; ++i) {
                int gr = rbase + i;
                if (gr < nrows) op[(size_t)gr * jb.ldo + tn * 16 + lr] = (f16)(acc[tn][i] + brs[i] * bsv[tn]);
            }
    }
}

// ---------------- layer-1 GCN aggregation (fp16 in/out): S[d] = dvd*sum dvs*h[s]; srow[d]=dvd*sum dvs ----------------
__global__ __launch_bounds__(256) void sgather(
    const int* __restrict__ rowptr, const int* __restrict__ esorted,
    const float* __restrict__ dinv, const __half* __restrict__ h16,
    __half* __restrict__ S, float* __restrict__ srow) {
    int d = (blockIdx.x * 256 + threadIdx.x) >> 6;
    int lane = threadIdx.x & 63;
    if (d >= NN) return;
    int i0 = rowptr[d], i1 = rowptr[d + 1];
    int nE = i1 - i0 + 1;  // + self-loop (last)
    float dvd = dinv[d];
    float ax = 0.f, ay = 0.f, ssum = 0.f;
    for (int j = 0; j < nE; ++j) {
        int s = (j < nE - 1) ? esorted[i0 + j] : d;
        float dvs = dinv[s];
        float2 f = __half22float2(((const __half2*)h16)[(size_t)s * 64 + lane]);
        ax = fmaf(dvs, f.x, ax);
        ay = fmaf(dvs, f.y, ay);
        ssum += dvs;
    }
    ((__half2*)S)[(size_t)d * 64 + lane] = __floats2half2_rn(dvd * ax, dvd * ay);
    if (lane == 0) srow[d] = dvd * ssum;
}

// ---------------- node-centric attention (fp16 kv): one wave per dst node; fp16+relu output ----------------
template<int L>
__global__ __launch_bounds__(256) void node_attn(
    const int* __restrict__ rowptr, const int* __restrict__ esorted,
    const float* __restrict__ dinv,
    const float* __restrict__ qn, const __half* __restrict__ kv,
    __half* __restrict__ outv) {
    int d = (blockIdx.x * 256 + threadIdx.x) >> 6;
    int lane = threadIdx.x & 63;
    if (d >= NN) return;
    int i0 = rowptr[d], i1 = rowptr[d + 1];
    int nE = i1 - i0 + 1;
    float dvd = dinv[d];
    float2 q2 = ((const float2*)(qn + (size_t)d * HID))[lane];
    float ax = 0.f, ay = 0.f;

    int sCur = (nE > 1) ? esorted[i0] : d;
    float dvs = dinv[sCur];
    float2 k2[L], v2[L];
    {
        const __half2* bp = (const __half2*)(kv + (size_t)sCur * KVH);
#pragma unroll
        for (int l = 0; l < L; ++l) {
            k2[l] = __half22float2(bp[l * 128 + lane]);
            v2[l] = __half22float2(bp[l * 128 + 64 + lane]);
        }
    }

    for (int j = 0; j < nE; ++j) {
        int sNext = (j + 2 <= nE - 1) ? esorted[i0 + j + 1] : d;
        float ndvs = dinv[sNext];
        float2 nk[L], nv[L];
        if (j + 1 < nE) {
            const __half2* np = (const __half2*)(kv + (size_t)sNext * KVH);
#pragma unroll
            for (int l = 0; l < L; ++l) {
                nk[l] = __half22float2(np[l * 128 + lane]);
                nv[l] = __half22float2(np[l * 128 + 64 + lane]);
            }
        }
        float sc[L];
#pragma unroll
        for (int l = 0; l < L; ++l) {
            float p = q2.x * k2[l].x + q2.y * k2[l].y;
            p += __shfl_xor(p, 1);
            p += __shfl_xor(p, 2);
            p += __shfl_xor(p, 4);
            sc[l] = p * 0.25f;  // 1/sqrt(16)
        }
        float m = sc[0];
#pragma unroll
        for (int l = 1; l < L; ++l) m = fmaxf(m, sc[l]);
        float den = 0.f;
#pragma unroll
        for (int l = 0; l < L; ++l) { sc[l] = __expf(sc[l] - m); den += sc[l]; }
        float w = dvd * dvs / den;
#pragma unroll
        for (int l = 0; l < L; ++l) {
            ax = fmaf(sc[l] * w, v2[l].x, ax);
            ay = fmaf(sc[l] * w, v2[l].y, ay);
        }
#pragma unroll
        for (int l = 0; l < L; ++l) { k2[l] = nk[l]; v2[l] = nv[l]; }
        dvs = ndvs;
    }
    ((__half2*)outv)[(size_t)d * 64 + lane] = __floats2half2_rn(fmaxf(ax, 0.f), fmaxf(ay, 0.f));
}

// ---------------- final: logits + log_softmax (fp16 input, post-relu) ----------------
__global__ __launch_bounds__(256) void final_out(const __half* __restrict__ xin,
                                                 const float* __restrict__ W2,
                                                 const float* __restrict__ b2,
                                                 float* __restrict__ out) {
    int wid = (blockIdx.x * 256 + threadIdx.x) >> 6;
    int lane = threadIdx.x & 63;
    if (wid >= NN) return;
    const __half2* xr = (const __half2*)(xin + (size_t)wid * HID);
    float acc = b2[lane];
#pragma unroll 8
    for (int i = 0; i < 64; ++i) {
        float2 xv = __half22float2(xr[i]);
        acc = fmaf(xv.x, W2[(2 * i) * 64 + lane], acc);
        acc = fmaf(xv.y, W2[(2 * i + 1) * 64 + lane], acc);
    }
    float m = acc;
#pragma unroll
    for (int sft = 32; sft; sft >>= 1) m = fmaxf(m, __shfl_xor(m, sft));
    float e = __expf(acc - m), den = e;
#pragma unroll
    for (int sft = 32; sft; sft >>= 1) den += __shfl_xor(den, sft);
    out[(size_t)wid * 64 + lane] = acc - m - logf(den);
}

extern "C" void kernel_launch(void* const* d_in, const int* in_sizes, int n_in,
                              void* d_out, int out_size, void* d_ws, size_t ws_size,
                              hipStream_t stream) {
    (void)in_sizes; (void)n_in; (void)out_size; (void)ws_size;
    const float* x  = (const float*)d_in[0];
    const int*   ei = (const int*)d_in[1];
    const float* W1 = (const float*)d_in[2];
    const float* b1 = (const float*)d_in[3];
    const float* Wq = (const float*)d_in[4];
    const float* bq = (const float*)d_in[5];
    const float* Wk = (const float*)d_in[6];
    const float* bk = (const float*)d_in[7];
    const float* Wv = (const float*)d_in[8];
    const float* bv = (const float*)d_in[9];
    const float* W2 = (const float*)d_in[10];
    const float* b2 = (const float*)d_in[11];
    float* out = (float*)d_out;

    // workspace layout
    int*    cnt     = (int*)d_ws;                  // 16384 words
    int*    fill    = cnt + 16384;
    int*    rowptr  = fill + 16384;
    int*    esorted = rowptr + 16384;              // 163840
    float*  dinv    = (float*)(esorted + 163840);  // 16384
    float*  srow    = dinv + 16384;                // 16384
    float*  qn      = srow + 16384;                // N128 f32
    f16*    xh      = (f16*)(qn + N128);           // N128 halves
    f16*    lvh0    = xh + N128;                   // 4 x N128 halves (post-relu)
    f16*    Sh      = lvh0 + 4 * (size_t)N128;     // N128
    f16*    kvb     = Sh + N128;                   // NN x 768
    f16*    Wt      = kvb + (size_t)NN * KVH;      // 10 x 16384
    auto lvh = [&](int i) { return lvh0 + (size_t)i * N128; };

    hipMemsetAsync(cnt, 0, 2 * 16384 * sizeof(int), stream);  // cnt + fill

    cnt_count<<<(EE + 255) / 256, 256, 0, stream>>>(ei + EE, cnt);
    make_dinv<<<(NN + 255) / 256, 256, 0, stream>>>(cnt, dinv);
    scan_rowptr<<<1, 256, 0, stream>>>(cnt, rowptr);
    scatter_edges<<<(EE + 255) / 256, 256, 0, stream>>>(ei, rowptr, fill, esorted);

    wprep<<<10, 256, 0, stream>>>(W1, Wq, Wk, Wv, Wt);
    tohalf<<<(N128 / 2 + 255) / 256, 256, 0, stream>>>(x, (__half*)xh);

    const int gx = (NN + 63) / 64;  // 157
    auto WT = [&](int m) { return Wt + (size_t)m * 16384; };  // 0=W1,1..3=Wq,4..6=Wk,7..9=Wv

    {   // lvh0 = relu(x @ W1 + b1), fp16
        GJobs jobs{};
        jobs.j[0] = {xh, WT(0), b1, nullptr, lvh(0), HID, 1};
        gemm_mfma<<<dim3(gx, 1), 256, 0, stream>>>(jobs, NN);
    }

    const int nblocks = (NN * 64 + 255) / 256;

    // ---- layer 1 (L=1: attention == identity -> GCN) ----
    sgather<<<nblocks, 256, 0, stream>>>(rowptr, esorted, dinv, (const __half*)lvh(0), (__half*)Sh, srow);
    {   // lvh1 = relu(S @ Wv1 + srow*bv1)
        GJobs jobs{};
        jobs.j[0] = {Sh, WT(7), bv, srow, lvh(1), HID, 1};
        gemm_mfma<<<dim3(gx, 1), 256, 0, stream>>>(jobs, NN);
    }

    // ---- layers 2,3 (attention over L levels, fp16 kv) ----
    for (int l = 1; l < 3; ++l) {
        int L = l + 1;
        GJobs jobs{};
        jobs.j[0] = {lvh(L - 1), WT(1 + l), bq + l * HID, nullptr, qn, HID, 0};
        for (int lev = 0; lev < L; ++lev) {
            jobs.j[1 + lev]     = {lvh(lev), WT(4 + l), bk + l * HID, nullptr, kvb + lev * 256,       KVH, 2};
            jobs.j[1 + L + lev] = {lvh(lev), WT(7 + l), bv + l * HID, nullptr, kvb + lev * 256 + 128, KVH, 2};
        }
        gemm_mfma<<<dim3(gx, 2 * L + 1), 256, 0, stream>>>(jobs, NN);

        if (L == 2) node_attn<2><<<nblocks, 256, 0, stream>>>(rowptr, esorted, dinv, qn, (const __half*)kvb, (__half*)lvh(2));
        if (L == 3) node_attn<3><<<nblocks, 256, 0, stream>>>(rowptr, esorted, dinv, qn, (const __half*)kvb, (__half*)lvh(3));
    }

    final_out<<<(NN * 64 + 255) / 256, 256, 0, stream>>>((const __half*)lvh(3), W2, b2, out);
}

// Round 5
// 220.085 us; speedup vs baseline: 2.8940x; 1.0479x over previous
//
#include <hip/hip_runtime.h>
#include <hip/hip_fp16.h>
#include <math.h>

#define NN 10000
#define EE 160000
#define HID 128
constexpr int N128 = NN * HID;
constexpr int KSTR = 384;  // k buffer: 3 levels x 128 halves per node

typedef _Float16 f16;
typedef f16 half8 __attribute__((ext_vector_type(8)));
typedef f16 f16x2 __attribute__((ext_vector_type(2)));
typedef float f32x4 __attribute__((ext_vector_type(4)));

#if __has_builtin(__builtin_amdgcn_fdot2)
__device__ inline float fdot2(f16x2 a, f16x2 b, float c) { return __builtin_amdgcn_fdot2(a, b, c, false); }
#else
__device__ inline float fdot2(f16x2 a, f16x2 b, float c) {
    return fmaf((float)a[0], (float)b[0], fmaf((float)a[1], (float)b[1], c));
}
#endif

// ---------------- degree count (by dst) ----------------
__global__ __launch_bounds__(256) void cnt_count(const int* __restrict__ dst, int* __restrict__ cnt) {
    int e = blockIdx.x * 256 + threadIdx.x;
    if (e < EE) atomicAdd(&cnt[dst[e]], 1);
}

__global__ __launch_bounds__(256) void make_dinv(const int* __restrict__ cnt, float* __restrict__ dinv) {
    int i = blockIdx.x * 256 + threadIdx.x;
    if (i < NN) dinv[i] = rsqrtf((float)cnt[i] + 1.0f);  // +1 self-loop
}

// ---------------- single-block exclusive scan -> rowptr ----------------
__global__ __launch_bounds__(256) void scan_rowptr(const int* __restrict__ cnt, int* __restrict__ rowptr) {
    __shared__ int part[256];
    const int PER = (NN + 255) / 256;  // 40
    int t = threadIdx.x;
    int base = t * PER;
    int sum = 0;
    for (int i = 0; i < PER; ++i) { int idx = base + i; if (idx < NN) sum += cnt[idx]; }
    part[t] = sum;
    __syncthreads();
    for (int ofs = 1; ofs < 256; ofs <<= 1) {
        int v = (t >= ofs) ? part[t - ofs] : 0;
        __syncthreads();
        part[t] += v;
        __syncthreads();
    }
    int run = (t > 0) ? part[t - 1] : 0;
    for (int i = 0; i < PER; ++i) {
        int idx = base + i;
        if (idx <= NN) rowptr[idx] = run;
        if (idx < NN) run += cnt[idx];
    }
}

__global__ __launch_bounds__(256) void scatter_edges(const int* __restrict__ ei,
                                                     const int* __restrict__ rowptr,
                                                     int* __restrict__ fill,
                                                     int* __restrict__ esorted) {
    int e = blockIdx.x * 256 + threadIdx.x;
    if (e < EE) {
        int s = ei[e], d = ei[EE + e];
        int pos = rowptr[d] + atomicAdd(&fill[d], 1);
        esorted[pos] = s;
    }
}

// ---------------- weight prep: Wt[mat][oc][k] = fp16(W[k][oc]), 10 matrices ----------------
__global__ __launch_bounds__(256) void wprep(const float* __restrict__ W1, const float* __restrict__ Wq,
                                             const float* __restrict__ Wk, const float* __restrict__ Wv,
                                             f16* __restrict__ Wt) {
    int b = blockIdx.x;  // 0=W1, 1..3=Wq[l], 4..6=Wk[l], 7..9=Wv[l]
    const float* src = (b == 0) ? W1
                     : (b < 4)  ? Wq + (size_t)(b - 1) * 16384
                     : (b < 7)  ? Wk + (size_t)(b - 4) * 16384
                                : Wv + (size_t)(b - 7) * 16384;
    f16* dst = Wt + (size_t)b * 16384;
    int t = threadIdx.x;
    int oc = t >> 1;
    int k0 = (t & 1) * 64;
    for (int kk = 0; kk < 64; ++kk) {
        int k = k0 + kk;
        dst[oc * 128 + k] = (f16)src[k * 128 + oc];
    }
}

// ---------------- x -> fp16 ----------------
__global__ __launch_bounds__(256) void tohalf(const float* __restrict__ in, __half* __restrict__ outh) {
    int i = blockIdx.x * 256 + threadIdx.x;
    if (i < N128 / 2) {
        float2 f = ((const float2*)in)[i];
        ((__half2*)outh)[i] = __floats2half2_rn(f.x, f.y);
    }
}

// ---------------- MFMA GEMM: out[n][oc] = sum_k in[n][k] * W[k][oc] + (rs*)bias[oc] ----------------
// in: fp16 row-major [nrows][128]; Wt: fp16 [oc][k]; mode 0=f32, 1=f16+relu, 2=f16 raw
struct GJob { const f16* in; const f16* Wt; const float* bias; const float* rowscale; void* out; int ldo; int mode; };
struct GJobs { GJob j[7]; };

__global__ __launch_bounds__(256) void gemm_mfma(GJobs jobs, int nrows) {
    const GJob jb = jobs.j[blockIdx.y];
    __shared__ f16 Xl[64 * 128];
    __shared__ f16 Wl[128 * 128];
    const int t = threadIdx.x;
    const int row0 = blockIdx.x * 64;

    half8 zero8;
#pragma unroll
    for (int z = 0; z < 8; ++z) zero8[z] = (f16)0.f;

#pragma unroll
    for (int it = 0; it < 4; ++it) {
        int idx = t + it * 256;
        int r = idx >> 4, c = idx & 15;
        int gr = row0 + r;
        half8 v = zero8;
        if (gr < nrows) v = *(const half8*)(jb.in + (size_t)gr * 128 + c * 8);
        *(half8*)((char*)Xl + r * 256 + ((c * 16) ^ ((r & 7) << 4))) = v;
    }
#pragma unroll
    for (int it = 0; it < 8; ++it) {
        int idx = t + it * 256;
        int r = idx >> 4, c = idx & 15;
        half8 v = *(const half8*)(jb.Wt + (size_t)r * 128 + c * 8);
        *(half8*)((char*)Wl + r * 256 + ((c * 16) ^ ((r & 7) << 4))) = v;
    }
    __syncthreads();

    const int w = t >> 6, l = t & 63;
    const int lr = l & 15;
    const int lk = l >> 4;

    f32x4 acc[8];
#pragma unroll
    for (int tn = 0; tn < 8; ++tn)
#pragma unroll
        for (int i = 0; i < 4; ++i) acc[tn][i] = 0.f;

    const int arow = w * 16 + lr;
    const int axor = (arow & 7) << 4;
    const int bxor = (lr & 7) << 4;

#pragma unroll
    for (int ks = 0; ks < 4; ++ks) {
        int koff = (ks * 4 + lk) * 16;
        half8 a = *(const half8*)((const char*)Xl + arow * 256 + (koff ^ axor));
#pragma unroll
        for (int tn = 0; tn < 8; ++tn) {
            int oc = tn * 16 + lr;
            half8 b = *(const half8*)((const char*)Wl + oc * 256 + (koff ^ bxor));
            acc[tn] = __builtin_amdgcn_mfma_f32_16x16x32_f16(a, b, acc[tn], 0, 0, 0);
        }
    }

    const int rbase = row0 + w * 16 + (lk << 2);
    float brs[4];
#pragma unroll
    for (int i = 0; i < 4; ++i)
        brs[i] = jb.rowscale ? ((rbase + i < nrows) ? jb.rowscale[rbase + i] : 0.f) : 1.0f;
    float bsv[8];
#pragma unroll
    for (int tn = 0; tn < 8; ++tn) bsv[tn] = jb.bias[tn * 16 + lr];

    if (jb.mode == 0) {
        float* op = (float*)jb.out;
#pragma unroll
        for (int tn = 0; tn < 8; ++tn)
#pragma unroll
            for (int i = 0; i < 4; ++i) {
                int gr = rbase + i;
                if (gr < nrows) op[(size_t)gr * jb.ldo + tn * 16 + lr] = acc[tn][i] + brs[i] * bsv[tn];
            }
    } else if (jb.mode == 1) {
        f16* op = (f16*)jb.out;
#pragma unroll
        for (int tn = 0; tn < 8; ++tn)
#pragma unroll
            for (int i = 0; i < 4; ++i) {
                int gr = rbase + i;
                if (gr < nrows) op[(size_t)gr * jb.ldo + tn * 16 + lr] = (f16)fmaxf(acc[tn][i] + brs[i] * bsv[tn], 0.f);
            }
    } else {
        f16* op = (f16*)jb.out;
#pragma unroll
        for (int tn = 0; tn < 8; ++tn)
#pragma unroll
            for (int i = 0; i < 4; ++i) {
                int gr = rbase + i;
                if (gr < nrows) op[(size_t)gr * jb.ldo + tn * 16 + lr] = (f16)(acc[tn][i] + brs[i] * bsv[tn]);
            }
    }
}

// ---------------- layer-1 GCN aggregation + srow (once): S=dvd*sum dvs*h[s]; srow=dvd*sum dvs ----------------
__global__ __launch_bounds__(256) void sgather(
    const int* __restrict__ rowptr, const int* __restrict__ esorted,
    const float* __restrict__ dinv, const __half* __restrict__ h16,
    __half* __restrict__ S, float* __restrict__ srow) {
    int d = (blockIdx.x * 256 + threadIdx.x) >> 6;
    int lane = threadIdx.x & 63;
    if (d >= NN) return;
    int i0 = rowptr[d], i1 = rowptr[d + 1];
    int nE = i1 - i0 + 1;  // + self-loop (last)
    float dvd = dinv[d];
    float ax = 0.f, ay = 0.f, ssum = 0.f;
    for (int j = 0; j < nE; ++j) {
        int s = (j < nE - 1) ? esorted[i0 + j] : d;
        float dvs = dinv[s];
        float2 f = __half22float2(((const __half2*)h16)[(size_t)s * 64 + lane]);
        ax = fmaf(dvs, f.x, ax);
        ay = fmaf(dvs, f.y, ay);
        ssum += dvs;
    }
    ((__half2*)S)[(size_t)d * 64 + lane] = __floats2half2_rn(dvd * ax, dvd * ay);
    if (lane == 0) srow[d] = dvd * ssum;
}

// ---------------- node attention, deferred-V: u[d] = sum_e norm * sum_l a_l * h_l[s] ----------------
template<int L>
__global__ __launch_bounds__(256) void node_attn2(
    const int* __restrict__ rowptr, const int* __restrict__ esorted,
    const float* __restrict__ dinv,
    const f16* __restrict__ qh, const f16* __restrict__ kb,
    const f16* __restrict__ h0, const f16* __restrict__ h1, const f16* __restrict__ h2,
    f16* __restrict__ uh) {
    int d = (blockIdx.x * 256 + threadIdx.x) >> 6;
    int lane = threadIdx.x & 63;
    if (d >= NN) return;
    const f16* hp0 = h0;
    const f16* hp1 = h1;
    const f16* hp2 = h2;
    int i0 = rowptr[d], i1 = rowptr[d + 1];
    int nE = i1 - i0 + 1;
    float dvd = dinv[d];
    f16x2 q2 = *(const f16x2*)(qh + (size_t)d * 128 + lane * 2);
    float ax = 0.f, ay = 0.f;

    int sCur = (nE > 1) ? esorted[i0] : d;
    float dvs = dinv[sCur];
    f16x2 k2[L], hh[L];
    {
        const f16* kp = kb + (size_t)sCur * KSTR;
#pragma unroll
        for (int l = 0; l < L; ++l) {
            k2[l] = *(const f16x2*)(kp + l * 128 + lane * 2);
            const f16* hb = (l == 0) ? hp0 : (l == 1) ? hp1 : hp2;
            hh[l] = *(const f16x2*)(hb + (size_t)sCur * 128 + lane * 2);
        }
    }

    for (int j = 0; j < nE; ++j) {
        int sNext = (j + 2 <= nE - 1) ? esorted[i0 + j + 1] : d;
        float ndvs = dinv[sNext];
        f16x2 nk[L], nh[L];
        if (j + 1 < nE) {
            const f16* np = kb + (size_t)sNext * KSTR;
#pragma unroll
            for (int l = 0; l < L; ++l) {
                nk[l] = *(const f16x2*)(np + l * 128 + lane * 2);
                const f16* hb = (l == 0) ? hp0 : (l == 1) ? hp1 : hp2;
                nh[l] = *(const f16x2*)(hb + (size_t)sNext * 128 + lane * 2);
            }
        }
        float sc[L];
#pragma unroll
        for (int l = 0; l < L; ++l) {
            float p = fdot2(q2, k2[l], 0.f);
            p += __shfl_xor(p, 1);
            p += __shfl_xor(p, 2);
            p += __shfl_xor(p, 4);
            sc[l] = p * 0.25f;  // 1/sqrt(16)
        }
        float m = sc[0];
#pragma unroll
        for (int l = 1; l < L; ++l) m = fmaxf(m, sc[l]);
        float den = 0.f;
#pragma unroll
        for (int l = 0; l < L; ++l) { sc[l] = __expf(sc[l] - m); den += sc[l]; }
        float w = dvd * dvs / den;
#pragma unroll
        for (int l = 0; l < L; ++l) {
            float wl = sc[l] * w;
            ax = fmaf(wl, (float)hh[l][0], ax);
            ay = fmaf(wl, (float)hh[l][1], ay);
        }
#pragma unroll
        for (int l = 0; l < L; ++l) { k2[l] = nk[l]; hh[l] = nh[l]; }
        dvs = ndvs;
    }
    f16x2 o; o[0] = (f16)ax; o[1] = (f16)ay;
    *(f16x2*)(uh + (size_t)d * 128 + lane * 2) = o;
}

// ---------------- final: logits + log_softmax (fp16 input, post-relu) ----------------
__global__ __launch_bounds__(256) void final_out(const __half* __restrict__ xin,
                                                 const float* __restrict__ W2,
                                                 const float* __restrict__ b2,
                                                 float* __restrict__ out) {
    int wid = (blockIdx.x * 256 + threadIdx.x) >> 6;
    int lane = threadIdx.x & 63;
    if (wid >= NN) return;
    const __half2* xr = (const __half2*)(xin + (size_t)wid * HID);
    float acc = b2[lane];
#pragma unroll 8
    for (int i = 0; i < 64; ++i) {
        float2 xv = __half22float2(xr[i]);
        acc = fmaf(xv.x, W2[(2 * i) * 64 + lane], acc);
        acc = fmaf(xv.y, W2[(2 * i + 1) * 64 + lane], acc);
    }
    float m = acc;
#pragma unroll
    for (int sft = 32; sft; sft >>= 1) m = fmaxf(m, __shfl_xor(m, sft));
    float e = __expf(acc - m), den = e;
#pragma unroll
    for (int sft = 32; sft; sft >>= 1) den += __shfl_xor(den, sft);
    out[(size_t)wid * 64 + lane] = acc - m - logf(den);
}

extern "C" void kernel_launch(void* const* d_in, const int* in_sizes, int n_in,
                              void* d_out, int out_size, void* d_ws, size_t ws_size,
                              hipStream_t stream) {
    (void)in_sizes; (void)n_in; (void)out_size; (void)ws_size;
    const float* x  = (const float*)d_in[0];
    const int*   ei = (const int*)d_in[1];
    const float* W1 = (const float*)d_in[2];
    const float* b1 = (const float*)d_in[3];
    const float* Wq = (const float*)d_in[4];
    const float* bq = (const float*)d_in[5];
    const float* Wk = (const float*)d_in[6];
    const float* bk = (const float*)d_in[7];
    const float* Wv = (const float*)d_in[8];
    const float* bv = (const float*)d_in[9];
    const float* W2 = (const float*)d_in[10];
    const float* b2 = (const float*)d_in[11];
    float* out = (float*)d_out;

    // workspace layout
    int*    cnt     = (int*)d_ws;                  // 16384 words
    int*    fill    = cnt + 16384;
    int*    rowptr  = fill + 16384;
    int*    esorted = rowptr + 16384;              // 163840
    float*  dinv    = (float*)(esorted + 163840);  // 16384
    float*  srow    = dinv + 16384;                // 16384
    f16*    xh      = (f16*)(srow + 16384);        // N128
    f16*    lvh0    = xh + N128;                   // 4 x N128 (post-relu)
    f16*    Sh      = lvh0 + 4 * (size_t)N128;     // N128
    f16*    qh      = Sh + N128;                   // N128
    f16*    uh      = qh + N128;                   // N128
    f16*    kb      = uh + N128;                   // NN x 384
    f16*    Wt      = kb + (size_t)NN * KSTR;      // 10 x 16384
    auto lvh = [&](int i) { return lvh0 + (size_t)i * N128; };

    hipMemsetAsync(cnt, 0, 2 * 16384 * sizeof(int), stream);  // cnt + fill

    cnt_count<<<(EE + 255) / 256, 256, 0, stream>>>(ei + EE, cnt);
    make_dinv<<<(NN + 255) / 256, 256, 0, stream>>>(cnt, dinv);
    scan_rowptr<<<1, 256, 0, stream>>>(cnt, rowptr);
    scatter_edges<<<(EE + 255) / 256, 256, 0, stream>>>(ei, rowptr, fill, esorted);

    wprep<<<10, 256, 0, stream>>>(W1, Wq, Wk, Wv, Wt);
    tohalf<<<(N128 / 2 + 255) / 256, 256, 0, stream>>>(x, (__half*)xh);

    const int gx = (NN + 63) / 64;  // 157
    auto WT = [&](int m) { return Wt + (size_t)m * 16384; };  // 0=W1,1..3=Wq,4..6=Wk,7..9=Wv

    {   // lvh0 = relu(x @ W1 + b1)
        GJobs jobs{};
        jobs.j[0] = {xh, WT(0), b1, nullptr, lvh(0), HID, 1};
        gemm_mfma<<<dim3(gx, 1), 256, 0, stream>>>(jobs, NN);
    }

    const int nblocks = (NN * 64 + 255) / 256;

    // ---- layer 1 (L=1: attention == identity -> GCN, deferred Wv1) ----
    sgather<<<nblocks, 256, 0, stream>>>(rowptr, esorted, dinv, (const __half*)lvh(0), (__half*)Sh, srow);
    {   // lvh1 = relu(S @ Wv1 + srow*bv1)
        GJobs jobs{};
        jobs.j[0] = {Sh, WT(7), bv, srow, lvh(1), HID, 1};
        gemm_mfma<<<dim3(gx, 1), 256, 0, stream>>>(jobs, NN);
    }

    // ---- layers 2,3: q/k GEMMs -> attention (aggregate raw h) -> deferred Wv GEMM ----
    for (int l = 1; l < 3; ++l) {
        int L = l + 1;
        GJobs jobs{};
        jobs.j[0] = {lvh(L - 1), WT(1 + l), bq + l * HID, nullptr, qh, HID, 2};
        for (int lev = 0; lev < L; ++lev)
            jobs.j[1 + lev] = {lvh(lev), WT(4 + l), bk + l * HID, nullptr, kb + lev * 128, KSTR, 2};
        gemm_mfma<<<dim3(gx, 1 + L), 256, 0, stream>>>(jobs, NN);

        if (L == 2) node_attn2<2><<<nblocks, 256, 0, stream>>>(rowptr, esorted, dinv, qh, kb,
                                                               lvh(0), lvh(1), lvh(1), uh);
        if (L == 3) node_attn2<3><<<nblocks, 256, 0, stream>>>(rowptr, esorted, dinv, qh, kb,
                                                               lvh(0), lvh(1), lvh(2), uh);

        GJobs vjob{};
        vjob.j[0] = {uh, WT(7 + l), bv + l * HID, srow, lvh(L), HID, 1};
        gemm_mfma<<<dim3(gx, 1), 256, 0, stream>>>(vjob, NN);
    }

    final_out<<<(NN * 64 + 255) / 256, 256, 0, stream>>>((const __half*)lvh(3), W2, b2, out);
}